// Round 3
// baseline (857.234 us; speedup 1.0000x reference)
//
#include <hip/hip_runtime.h>
#include <math.h>

#define NROW 1024
#define INF_BITS 0x7F800000u
#define WINDOW   4.0e-3f     // > 2*max |d2_f32 - d2_f64| (bound ~8e-4)
#define CLAMP_EPS 1e-12f

typedef float nf4 __attribute__((ext_vector_type(4)));   // native vec for nontemporal builtins

__device__ __forceinline__ unsigned long long ull_min(unsigned long long a, unsigned long long b) {
    return a < b ? a : b;
}

// ---------------------------------------------------------------------------
// Exact top-16 selection per row.
// K[tt] = f32 d^2 bit pattern (positive => u32 order == float order), column
// j = tt*64 + lane; INF_BITS for invalid. Fast path: ballot-bisection on the
// f32 keys; if the boundary has no f32 ambiguity AND a WINDOW-sized gap above
// the 16th value, the f32 selection provably equals the f64 selection.
// Otherwise: rare exact path — redistribute all candidates (keys <= V+WINDOW,
// >=16, <=64 of them) one per lane, recompute their d^2 in f64 from global
// (L2-hot), extract 16 winners by (f64 bits, j) — jax top_k tie semantics.
// Uses lane, nbase, rowc, sqr64 from enclosing scope. Caller guarantees the
// row is valid (>=511 finite keys) and the branch is wave-uniform.
// ---------------------------------------------------------------------------
#define SELECT_ROW(K, RLOC, SELOUT)                                                     \
    {                                                                                   \
        unsigned mn = 0xFFFFFFFFu, mx = 0u;                                             \
        _Pragma("unroll")                                                               \
        for (int tt = 0; tt < 16; ++tt) {                                               \
            const unsigned kk_ = K[tt];                                                 \
            mn = kk_ < mn ? kk_ : mn;                                                   \
            const unsigned kf_ = (kk_ < INF_BITS) ? kk_ : 0u;                           \
            mx = kf_ > mx ? kf_ : mx;                                                   \
        }                                                                               \
        _Pragma("unroll")                                                               \
        for (int d = 1; d < 64; d <<= 1) {                                              \
            const unsigned omn = (unsigned)__shfl_xor((int)mn, d);                      \
            const unsigned omx = (unsigned)__shfl_xor((int)mx, d);                      \
            mn = omn < mn ? omn : mn;                                                   \
            mx = omx > mx ? omx : mx;                                                   \
        }                                                                               \
        unsigned lo = mn, hi = mx + 1u;   /* count(<lo)=0<16<=count(<hi)=cntF>=511 */   \
        while (hi - lo > 1u) {                                                          \
            const unsigned mid = lo + ((hi - lo) >> 1);                                 \
            int cnt = 0;                                                                \
            _Pragma("unroll")                                                           \
            for (int tt = 0; tt < 16; ++tt)                                             \
                cnt += __popcll(__ballot(K[tt] < mid));                                 \
            if (cnt >= 16) hi = mid; else lo = mid;                                     \
        }                                                                               \
        const unsigned V = lo;            /* 16th smallest f32 key (bit pattern) */     \
        const float Vw = __uint_as_float(V) + WINDOW;                                   \
        int cS = 0, nE = 0, cW = 0;                                                     \
        unsigned ltm = 0u, eqm = 0u, cm = 0u;                                           \
        _Pragma("unroll")                                                               \
        for (int tt = 0; tt < 16; ++tt) {                                               \
            const unsigned kk_ = K[tt];                                                 \
            const bool l_ = kk_ < V;                                                    \
            const bool e_ = kk_ == V;                                                   \
            const bool c_ = __uint_as_float(kk_) <= Vw;  /* inf never qualifies */      \
            cS += __popcll(__ballot(l_));                                               \
            nE += __popcll(__ballot(e_));                                               \
            cW += __popcll(__ballot(c_));                                               \
            ltm |= (l_ ? 1u : 0u) << tt;                                                \
            eqm |= (e_ ? 1u : 0u) << tt;                                                \
            cm  |= (c_ ? 1u : 0u) << tt;                                                \
        }                                                                               \
        if (cS + nE == 16 && cW == 16) {                                                \
            /* unambiguous: selected f64 values < V+e, excluded > V+WINDOW-e */         \
            SELOUT = ltm | eqm;                                                         \
        } else {                                                                        \
            /* enumerate candidates, one per lane (nC in [16,64] for this data) */      \
            int myj = -1;                                                               \
            {                                                                           \
                int cum = 0;                                                            \
                _Pragma("unroll")                                                       \
                for (int tt = 0; tt < 16; ++tt) {                                       \
                    const unsigned long long bm = __ballot((cm >> tt) & 1u);            \
                    const int pc = __popcll(bm);                                        \
                    if (myj < 0 && lane >= cum && lane < cum + pc) {                    \
                        unsigned long long mm = bm;                                     \
                        for (int z = lane - cum; z > 0; --z) mm &= mm - 1ull;           \
                        myj = tt * 64 + (__ffsll((unsigned long long)mm) - 1);          \
                    }                                                                   \
                    cum += pc;                                                          \
                }                                                                       \
            }                                                                           \
            unsigned long long dbits = ~0ull;                                           \
            if (myj >= 0) {                                                             \
                const float4* cp = (const float4*)(nbase + (size_t)myj * 64);           \
                double sq_ = 0.0, dt_ = 0.0;                                            \
                _Pragma("unroll")                                                       \
                for (int f = 0; f < 8; ++f) {                                           \
                    const float4 v = cp[f];                                             \
                    const float4 a = rowc[(RLOC) * 8 + f];                              \
                    sq_ = fma((double)v.x, (double)v.x, sq_);                           \
                    sq_ = fma((double)v.y, (double)v.y, sq_);                           \
                    sq_ = fma((double)v.z, (double)v.z, sq_);                           \
                    sq_ = fma((double)v.w, (double)v.w, sq_);                           \
                    dt_ = fma((double)v.x, (double)a.x, dt_);                           \
                    dt_ = fma((double)v.y, (double)a.y, dt_);                           \
                    dt_ = fma((double)v.z, (double)a.z, dt_);                           \
                    dt_ = fma((double)v.w, (double)a.w, dt_);                           \
                }                                                                       \
                double d64 = fma(-2.0, dt_, sqr64[RLOC] + sq_);                         \
                d64 = fmax(d64, (double)CLAMP_EPS);                                     \
                dbits = (unsigned long long)__double_as_longlong(d64);                  \
            }                                                                           \
            unsigned selb = 0u;                                                         \
            bool act = (myj >= 0);                                                      \
            for (int round = 0; round < 16; ++round) {                                  \
                unsigned long long best = act ? dbits : ~0ull;                          \
                _Pragma("unroll")                                                       \
                for (int d = 1; d < 64; d <<= 1)                                        \
                    best = ull_min(best,                                                \
                        (unsigned long long)__shfl_xor((long long)best, d));            \
                int pj = (act && dbits == best) ? myj : 0x7FFFFFFF;                     \
                _Pragma("unroll")                                                       \
                for (int d = 1; d < 64; d <<= 1) {                                      \
                    const int o = __shfl_xor(pj, d);                                    \
                    pj = o < pj ? o : pj;                                               \
                }                                                                       \
                if (myj == pj) act = false;                                             \
                if (lane == (pj & 63)) selb |= 1u << (pj >> 6);                         \
            }                                                                           \
            SELOUT = selb;                                                              \
        }                                                                               \
    }

// 4-row dot accumulation for one (f) step against two staged columns
#define DOT4(vX, a, dA, dB, vY)                                                         \
    dA = fmaf(vX.x, a.x, dA); dA = fmaf(vX.y, a.y, dA);                                 \
    dA = fmaf(vX.z, a.z, dA); dA = fmaf(vX.w, a.w, dA);                                 \
    dB = fmaf(vY.x, a.x, dB); dB = fmaf(vY.y, a.y, dB);                                 \
    dB = fmaf(vY.z, a.z, dB); dB = fmaf(vY.w, a.w, dB);

#define MAKE_KEYS(KA, DA, DB, SQR, ROW)                                                 \
    {                                                                                   \
        float e_;                                                                       \
        e_ = fmaxf(fmaf(-2.f, DA, SQR + sA), CLAMP_EPS);                                \
        KA[2 * t]     = (vA_ && jA != (ROW)) ? __float_as_uint(e_) : INF_BITS;          \
        e_ = fmaxf(fmaf(-2.f, DB, SQR + sB), CLAMP_EPS);                                \
        KA[2 * t + 1] = (vB_ && jB != (ROW)) ? __float_as_uint(e_) : INF_BITS;          \
    }

__global__ __launch_bounds__(256, 4) void edge_knn_kernel(
    const float* __restrict__ nodes,
    const int*   __restrict__ mask,
    float*       __restrict__ out)
{
    const int tid  = threadIdx.x;
    const int lane = tid & 63;
    const int wid  = tid >> 6;
    const int blk  = blockIdx.x;
    const int b    = blk >> 6;                 // 64 blocks per batch
    const int rowbase = (blk & 63) * 16;       // 16 rows per block

    const int* maskb = mask + b * NROW;
    float* edges = out + (size_t)b * NROW * NROW;
    float* adjm  = out + (size_t)64 * NROW * NROW + (size_t)b * NROW * NROW;

    // ---- fast path: all 16 rows masked -> zero-fill (d_out is poisoned)
    int anyv = 0;
#pragma unroll
    for (int r = 0; r < 16; ++r) anyv |= maskb[rowbase + r];
    if (!anyv) {
        const nf4 z = {0.f, 0.f, 0.f, 0.f};
#pragma unroll
        for (int r = 0; r < 16; ++r) {
            nf4* e4 = reinterpret_cast<nf4*>(edges + (size_t)(rowbase + r) * NROW);
            nf4* a4 = reinterpret_cast<nf4*>(adjm  + (size_t)(rowbase + r) * NROW);
            __builtin_nontemporal_store(z, e4 + tid);   // 256 float4 per row-array
            __builtin_nontemporal_store(z, a4 + tid);
        }
        return;
    }

    __shared__ float4 tile[128 * 8];    // 16 KB, swizzled: [c*8 + (f ^ (c&7))]
    __shared__ float4 rowc[16 * 8];     // 2 KB: 16 row coord vectors
    __shared__ float  sqc[NROW];        // 4 KB: per-column |cj|^2 (f32)
    __shared__ float  sqr32[16];
    __shared__ double sqr64[16];

    const float* nbase = nodes + (size_t)b * NROW * 64;

    // stage this block's 16 rows
    if (tid < 128) {
        const int r = tid >> 3, f = tid & 7;
        rowc[tid] = ((const float4*)(nbase + (size_t)(rowbase + r) * 64))[f];
    }
    // column validity bits: bit tt <-> column j = tt*64 + lane
    unsigned mb = 0u;
#pragma unroll
    for (int tt = 0; tt < 16; ++tt)
        mb |= (maskb[tt * 64 + lane] != 0 ? 1u : 0u) << tt;
    __syncthreads();

    if (tid < 16) {
        double s = 0.0;
#pragma unroll
        for (int f = 0; f < 8; ++f) {
            const float4 v = rowc[tid * 8 + f];
            s = fma((double)v.x, (double)v.x, s);
            s = fma((double)v.y, (double)v.y, s);
            s = fma((double)v.z, (double)v.z, s);
            s = fma((double)v.w, (double)v.w, s);
        }
        sqr64[tid] = s;
        sqr32[tid] = (float)s;
    }
    // per-column f32 squared norms (L2-hot re-read, once per block)
#pragma unroll
    for (int q = 0; q < 4; ++q) {
        const int c = tid + q * 256;
        const float4* cp = (const float4*)(nbase + (size_t)c * 64);
        float s = 0.f;
#pragma unroll
        for (int f = 0; f < 8; ++f) {
            const float4 v = cp[f];
            s = fmaf(v.x, v.x, s); s = fmaf(v.y, v.y, s);
            s = fmaf(v.z, v.z, s); s = fmaf(v.w, v.w, s);
        }
        sqc[c] = s;
    }
    __syncthreads();

    const int w4   = wid * 4;
    const int row0 = rowbase + w4;
    const bool rv0 = maskb[row0 + 0] != 0;
    const bool rv1 = maskb[row0 + 1] != 0;
    const bool rv2 = maskb[row0 + 2] != 0;
    const bool rv3 = maskb[row0 + 3] != 0;
    const float sqr0 = sqr32[w4 + 0], sqr1 = sqr32[w4 + 1];
    const float sqr2 = sqr32[w4 + 2], sqr3 = sqr32[w4 + 3];

    unsigned k0[16], k1[16], k2[16], k3[16];

#pragma unroll
    for (int t = 0; t < 8; ++t) {
        const unsigned pairb = (mb >> (2 * t)) & 3u;
        // block-uniform (mb identical per-lane across waves): skip dead tiles
        if (__ballot(pairb != 0u) == 0ull) {
            k0[2*t] = INF_BITS; k0[2*t+1] = INF_BITS;
            k1[2*t] = INF_BITS; k1[2*t+1] = INF_BITS;
            k2[2*t] = INF_BITS; k2[2*t+1] = INF_BITS;
            k3[2*t] = INF_BITS; k3[2*t+1] = INF_BITS;
            continue;
        }
        __syncthreads();   // previous tile consumed
#pragma unroll
        for (int q = 0; q < 4; ++q) {
            const int slot = q * 256 + tid;
            const int c  = slot >> 3;
            const int fp = slot & 7;
            const int f  = fp ^ (c & 7);
            tile[slot] = ((const float4*)(nbase + (size_t)(t * 128 + c) * 64))[f];
        }
        __syncthreads();

        float d00 = 0.f, d01 = 0.f, d10 = 0.f, d11 = 0.f;
        float d20 = 0.f, d21 = 0.f, d30 = 0.f, d31 = 0.f;
        const int swz = lane & 7;  // (64+lane)&7 == lane&7
#pragma unroll
        for (int f = 0; f < 8; ++f) {
            const float4 vA = tile[lane * 8 + (f ^ swz)];
            const float4 vB = tile[(64 + lane) * 8 + (f ^ swz)];
            const float4 a0 = rowc[(w4 + 0) * 8 + f];   // broadcast reads
            const float4 a1 = rowc[(w4 + 1) * 8 + f];
            const float4 a2 = rowc[(w4 + 2) * 8 + f];
            const float4 a3 = rowc[(w4 + 3) * 8 + f];
            DOT4(vA, a0, d00, d01, vB);
            DOT4(vA, a1, d10, d11, vB);
            DOT4(vA, a2, d20, d21, vB);
            DOT4(vA, a3, d30, d31, vB);
        }
        const float sA = sqc[t * 128 + lane];
        const float sB = sqc[t * 128 + 64 + lane];
        const int jA = t * 128 + lane, jB = jA + 64;
        const bool vA_ = (pairb & 1u) != 0u;
        const bool vB_ = (pairb & 2u) != 0u;
        MAKE_KEYS(k0, d00, d01, sqr0, row0 + 0);
        MAKE_KEYS(k1, d10, d11, sqr1, row0 + 1);
        MAKE_KEYS(k2, d20, d21, sqr2, row0 + 2);
        MAKE_KEYS(k3, d30, d31, sqr3, row0 + 3);
    }

    // ---- selection (wave-uniform per-row branches)
    unsigned sel0 = 0u, sel1 = 0u, sel2 = 0u, sel3 = 0u;
    if (rv0) SELECT_ROW(k0, w4 + 0, sel0);
    if (rv1) SELECT_ROW(k1, w4 + 1, sel1);
    if (rv2) SELECT_ROW(k2, w4 + 2, sel2);
    if (rv3) SELECT_ROW(k3, w4 + 3, sel3);

    // ---- dense output (coalesced dword streams, every element written)
#pragma unroll
    for (int tt = 0; tt < 16; ++tt) {
        const int j = tt * 64 + lane;
        {
            const bool s = (sel0 >> tt) & 1u;
            const float dv = s ? sqrtf(__uint_as_float(k0[tt])) : 0.f;
            __builtin_nontemporal_store(dv, edges + (size_t)(row0 + 0) * NROW + j);
            __builtin_nontemporal_store(s ? 1.f : 0.f, adjm + (size_t)(row0 + 0) * NROW + j);
        }
        {
            const bool s = (sel1 >> tt) & 1u;
            const float dv = s ? sqrtf(__uint_as_float(k1[tt])) : 0.f;
            __builtin_nontemporal_store(dv, edges + (size_t)(row0 + 1) * NROW + j);
            __builtin_nontemporal_store(s ? 1.f : 0.f, adjm + (size_t)(row0 + 1) * NROW + j);
        }
        {
            const bool s = (sel2 >> tt) & 1u;
            const float dv = s ? sqrtf(__uint_as_float(k2[tt])) : 0.f;
            __builtin_nontemporal_store(dv, edges + (size_t)(row0 + 2) * NROW + j);
            __builtin_nontemporal_store(s ? 1.f : 0.f, adjm + (size_t)(row0 + 2) * NROW + j);
        }
        {
            const bool s = (sel3 >> tt) & 1u;
            const float dv = s ? sqrtf(__uint_as_float(k3[tt])) : 0.f;
            __builtin_nontemporal_store(dv, edges + (size_t)(row0 + 3) * NROW + j);
            __builtin_nontemporal_store(s ? 1.f : 0.f, adjm + (size_t)(row0 + 3) * NROW + j);
        }
    }
}

extern "C" void kernel_launch(void* const* d_in, const int* in_sizes, int n_in,
                              void* d_out, int out_size, void* d_ws, size_t ws_size,
                              hipStream_t stream)
{
    const float* nodes = (const float*)d_in[0];
    const int*   mask  = (const int*)d_in[1];
    float* out = (float*)d_out;

    dim3 grid(64 * 64);    // 64 batches x 64 blocks (16 rows each)
    dim3 block(256);
    hipLaunchKernelGGL(edge_knn_kernel, grid, block, 0, stream, nodes, mask, out);
}

// Round 4
// 399.250 us; speedup vs baseline: 2.1471x; 2.1471x over previous
//
#include <hip/hip_runtime.h>
#include <math.h>

#define NROW 1024
#define INF_BITS 0x7F800000u
#define WINDOW   4.0e-3f     // > 2*max |d2_f32 - d2_f64| (bound ~8e-4)
#define CLAMP_EPS 1e-12f

typedef float nf4 __attribute__((ext_vector_type(4)));   // native vec for nontemporal builtins

__device__ __forceinline__ unsigned long long ull_min(unsigned long long a, unsigned long long b) {
    return a < b ? a : b;
}

// ---------------------------------------------------------------------------
// Exact top-16 selection per row.
// K[tt] = f32 d^2 bit pattern (positive => u32 order == float order), column
// j = tt*64 + lane; INF_BITS for invalid. Fast path: ballot-bisection on the
// f32 keys; if the boundary has no f32 ambiguity AND a WINDOW-sized gap above
// the 16th value, the f32 selection provably equals the f64 selection.
// Otherwise: rare exact path — redistribute all candidates (keys <= V+WINDOW,
// >=16, <=64 of them) one per lane, recompute their d^2 in f64 from global
// (L2-hot), extract 16 winners by (f64 bits, j) — jax top_k tie semantics.
// Uses lane, nbase, rowc, sqr64 from enclosing scope. Caller guarantees the
// row is valid (>=511 finite keys) and the branch is wave-uniform.
// ---------------------------------------------------------------------------
#define SELECT_ROW(K, RLOC, SELOUT)                                                     \
    {                                                                                   \
        unsigned mn = 0xFFFFFFFFu, mx = 0u;                                             \
        _Pragma("unroll")                                                               \
        for (int tt = 0; tt < 16; ++tt) {                                               \
            const unsigned kk_ = K[tt];                                                 \
            mn = kk_ < mn ? kk_ : mn;                                                   \
            const unsigned kf_ = (kk_ < INF_BITS) ? kk_ : 0u;                           \
            mx = kf_ > mx ? kf_ : mx;                                                   \
        }                                                                               \
        _Pragma("unroll")                                                               \
        for (int d = 1; d < 64; d <<= 1) {                                              \
            const unsigned omn = (unsigned)__shfl_xor((int)mn, d);                      \
            const unsigned omx = (unsigned)__shfl_xor((int)mx, d);                      \
            mn = omn < mn ? omn : mn;                                                   \
            mx = omx > mx ? omx : mx;                                                   \
        }                                                                               \
        unsigned lo = mn, hi = mx + 1u;   /* count(<lo)=0<16<=count(<hi)=cntF>=511 */   \
        while (hi - lo > 1u) {                                                          \
            const unsigned mid = lo + ((hi - lo) >> 1);                                 \
            int cnt = 0;                                                                \
            _Pragma("unroll")                                                           \
            for (int tt = 0; tt < 16; ++tt)                                             \
                cnt += __popcll(__ballot(K[tt] < mid));                                 \
            if (cnt >= 16) hi = mid; else lo = mid;                                     \
        }                                                                               \
        const unsigned V = lo;            /* 16th smallest f32 key (bit pattern) */     \
        const float Vw = __uint_as_float(V) + WINDOW;                                   \
        int cS = 0, nE = 0, cW = 0;                                                     \
        unsigned ltm = 0u, eqm = 0u, cm = 0u;                                           \
        _Pragma("unroll")                                                               \
        for (int tt = 0; tt < 16; ++tt) {                                               \
            const unsigned kk_ = K[tt];                                                 \
            const bool l_ = kk_ < V;                                                    \
            const bool e_ = kk_ == V;                                                   \
            const bool c_ = __uint_as_float(kk_) <= Vw;  /* inf never qualifies */      \
            cS += __popcll(__ballot(l_));                                               \
            nE += __popcll(__ballot(e_));                                               \
            cW += __popcll(__ballot(c_));                                               \
            ltm |= (l_ ? 1u : 0u) << tt;                                                \
            eqm |= (e_ ? 1u : 0u) << tt;                                                \
            cm  |= (c_ ? 1u : 0u) << tt;                                                \
        }                                                                               \
        if (cS + nE == 16 && cW == 16) {                                                \
            /* unambiguous: selected f64 values < V+e, excluded > V+WINDOW-e */         \
            SELOUT = ltm | eqm;                                                         \
        } else {                                                                        \
            /* enumerate candidates, one per lane (nC in [16,64] for this data) */      \
            int myj = -1;                                                               \
            {                                                                           \
                int cum = 0;                                                            \
                _Pragma("unroll")                                                       \
                for (int tt = 0; tt < 16; ++tt) {                                       \
                    const unsigned long long bm = __ballot((cm >> tt) & 1u);            \
                    const int pc = __popcll(bm);                                        \
                    if (myj < 0 && lane >= cum && lane < cum + pc) {                    \
                        unsigned long long mm = bm;                                     \
                        for (int z = lane - cum; z > 0; --z) mm &= mm - 1ull;           \
                        myj = tt * 64 + (__ffsll((unsigned long long)mm) - 1);          \
                    }                                                                   \
                    cum += pc;                                                          \
                }                                                                       \
            }                                                                           \
            unsigned long long dbits = ~0ull;                                           \
            if (myj >= 0) {                                                             \
                const float4* cp = (const float4*)(nbase + (size_t)myj * 64);           \
                double sq_ = 0.0, dt_ = 0.0;                                            \
                _Pragma("unroll")                                                       \
                for (int f = 0; f < 8; ++f) {                                           \
                    const float4 v = cp[f];                                             \
                    const float4 a = rowc[(RLOC) * 8 + f];                              \
                    sq_ = fma((double)v.x, (double)v.x, sq_);                           \
                    sq_ = fma((double)v.y, (double)v.y, sq_);                           \
                    sq_ = fma((double)v.z, (double)v.z, sq_);                           \
                    sq_ = fma((double)v.w, (double)v.w, sq_);                           \
                    dt_ = fma((double)v.x, (double)a.x, dt_);                           \
                    dt_ = fma((double)v.y, (double)a.y, dt_);                           \
                    dt_ = fma((double)v.z, (double)a.z, dt_);                           \
                    dt_ = fma((double)v.w, (double)a.w, dt_);                           \
                }                                                                       \
                double d64 = fma(-2.0, dt_, sqr64[RLOC] + sq_);                         \
                d64 = fmax(d64, (double)CLAMP_EPS);                                     \
                dbits = (unsigned long long)__double_as_longlong(d64);                  \
            }                                                                           \
            unsigned selb = 0u;                                                         \
            bool act = (myj >= 0);                                                      \
            for (int round = 0; round < 16; ++round) {                                  \
                unsigned long long best = act ? dbits : ~0ull;                          \
                _Pragma("unroll")                                                       \
                for (int d = 1; d < 64; d <<= 1)                                        \
                    best = ull_min(best,                                                \
                        (unsigned long long)__shfl_xor((long long)best, d));            \
                int pj = (act && dbits == best) ? myj : 0x7FFFFFFF;                     \
                _Pragma("unroll")                                                       \
                for (int d = 1; d < 64; d <<= 1) {                                      \
                    const int o = __shfl_xor(pj, d);                                    \
                    pj = o < pj ? o : pj;                                               \
                }                                                                       \
                if (myj == pj) act = false;                                             \
                if (lane == (pj & 63)) selb |= 1u << (pj >> 6);                         \
            }                                                                           \
            SELOUT = selb;                                                              \
        }                                                                               \
    }

// 4-row dot accumulation for one (f) step against two staged columns
#define DOT4(vX, a, dA, dB, vY)                                                         \
    dA = fmaf(vX.x, a.x, dA); dA = fmaf(vX.y, a.y, dA);                                 \
    dA = fmaf(vX.z, a.z, dA); dA = fmaf(vX.w, a.w, dA);                                 \
    dB = fmaf(vY.x, a.x, dB); dB = fmaf(vY.y, a.y, dB);                                 \
    dB = fmaf(vY.z, a.z, dB); dB = fmaf(vY.w, a.w, dB);

#define MAKE_KEYS(KA, DA, DB, SQR, ROW)                                                 \
    {                                                                                   \
        float e_;                                                                       \
        e_ = fmaxf(fmaf(-2.f, DA, SQR + sA), CLAMP_EPS);                                \
        KA[2 * t]     = (vA_ && jA != (ROW)) ? __float_as_uint(e_) : INF_BITS;          \
        e_ = fmaxf(fmaf(-2.f, DB, SQR + sB), CLAMP_EPS);                                \
        KA[2 * t + 1] = (vB_ && jB != (ROW)) ? __float_as_uint(e_) : INF_BITS;          \
    }

__global__ __launch_bounds__(256, 2) void edge_knn_kernel(
    const float* __restrict__ nodes,
    const int*   __restrict__ mask,
    float*       __restrict__ out)
{
    const int tid  = threadIdx.x;
    const int lane = tid & 63;
    const int wid  = tid >> 6;
    const int blk  = blockIdx.x;
    const int b    = blk >> 6;                 // 64 blocks per batch
    const int rowbase = (blk & 63) * 16;       // 16 rows per block

    const int* maskb = mask + b * NROW;
    float* edges = out + (size_t)b * NROW * NROW;
    float* adjm  = out + (size_t)64 * NROW * NROW + (size_t)b * NROW * NROW;

    // ---- fast path: all 16 rows masked -> zero-fill (d_out is poisoned)
    int anyv = 0;
#pragma unroll
    for (int r = 0; r < 16; ++r) anyv |= maskb[rowbase + r];
    if (!anyv) {
        const nf4 z = {0.f, 0.f, 0.f, 0.f};
#pragma unroll
        for (int r = 0; r < 16; ++r) {
            nf4* e4 = reinterpret_cast<nf4*>(edges + (size_t)(rowbase + r) * NROW);
            nf4* a4 = reinterpret_cast<nf4*>(adjm  + (size_t)(rowbase + r) * NROW);
            __builtin_nontemporal_store(z, e4 + tid);   // 256 float4 per row-array
            __builtin_nontemporal_store(z, a4 + tid);
        }
        return;
    }

    __shared__ float4 tile[128 * 8];    // 16 KB, swizzled: [c*8 + (f ^ (c&7))]
    __shared__ float4 rowc[16 * 8];     // 2 KB: 16 row coord vectors
    __shared__ float  sqc[NROW];        // 4 KB: per-column |cj|^2 (f32)
    __shared__ float  sqr32[16];
    __shared__ double sqr64[16];

    const float* nbase = nodes + (size_t)b * NROW * 64;

    // stage this block's 16 rows
    if (tid < 128) {
        const int r = tid >> 3, f = tid & 7;
        rowc[tid] = ((const float4*)(nbase + (size_t)(rowbase + r) * 64))[f];
    }
    // column validity bits: bit tt <-> column j = tt*64 + lane
    unsigned mb = 0u;
#pragma unroll
    for (int tt = 0; tt < 16; ++tt)
        mb |= (maskb[tt * 64 + lane] != 0 ? 1u : 0u) << tt;
    __syncthreads();

    if (tid < 16) {
        double s = 0.0;
#pragma unroll
        for (int f = 0; f < 8; ++f) {
            const float4 v = rowc[tid * 8 + f];
            s = fma((double)v.x, (double)v.x, s);
            s = fma((double)v.y, (double)v.y, s);
            s = fma((double)v.z, (double)v.z, s);
            s = fma((double)v.w, (double)v.w, s);
        }
        sqr64[tid] = s;
        sqr32[tid] = (float)s;
    }
    // per-column f32 squared norms (L2/L3-hot re-read, once per block)
#pragma unroll
    for (int q = 0; q < 4; ++q) {
        const int c = tid + q * 256;
        const float4* cp = (const float4*)(nbase + (size_t)c * 64);
        float s = 0.f;
#pragma unroll
        for (int f = 0; f < 8; ++f) {
            const float4 v = cp[f];
            s = fmaf(v.x, v.x, s); s = fmaf(v.y, v.y, s);
            s = fmaf(v.z, v.z, s); s = fmaf(v.w, v.w, s);
        }
        sqc[c] = s;
    }
    __syncthreads();

    const int w4   = wid * 4;
    const int row0 = rowbase + w4;
    const bool rv0 = maskb[row0 + 0] != 0;
    const bool rv1 = maskb[row0 + 1] != 0;
    const bool rv2 = maskb[row0 + 2] != 0;
    const bool rv3 = maskb[row0 + 3] != 0;
    const float sqr0 = sqr32[w4 + 0], sqr1 = sqr32[w4 + 1];
    const float sqr2 = sqr32[w4 + 2], sqr3 = sqr32[w4 + 3];

    unsigned k0[16], k1[16], k2[16], k3[16];

#pragma unroll
    for (int t = 0; t < 8; ++t) {
        const unsigned pairb = (mb >> (2 * t)) & 3u;
        // block-uniform (prefix mask: all waves see the same 128 columns): skip dead tiles
        if (__ballot(pairb != 0u) == 0ull) {
            k0[2*t] = INF_BITS; k0[2*t+1] = INF_BITS;
            k1[2*t] = INF_BITS; k1[2*t+1] = INF_BITS;
            k2[2*t] = INF_BITS; k2[2*t+1] = INF_BITS;
            k3[2*t] = INF_BITS; k3[2*t+1] = INF_BITS;
            continue;
        }
        __syncthreads();   // previous tile consumed
#pragma unroll
        for (int q = 0; q < 4; ++q) {
            const int slot = q * 256 + tid;
            const int c  = slot >> 3;
            const int fp = slot & 7;
            const int f  = fp ^ (c & 7);
            tile[slot] = ((const float4*)(nbase + (size_t)(t * 128 + c) * 64))[f];
        }
        __syncthreads();

        float d00 = 0.f, d01 = 0.f, d10 = 0.f, d11 = 0.f;
        float d20 = 0.f, d21 = 0.f, d30 = 0.f, d31 = 0.f;
        const int swz = lane & 7;  // (64+lane)&7 == lane&7
#pragma unroll
        for (int f = 0; f < 8; ++f) {
            const float4 vA = tile[lane * 8 + (f ^ swz)];
            const float4 vB = tile[(64 + lane) * 8 + (f ^ swz)];
            const float4 a0 = rowc[(w4 + 0) * 8 + f];   // wave-uniform broadcast reads
            const float4 a1 = rowc[(w4 + 1) * 8 + f];
            const float4 a2 = rowc[(w4 + 2) * 8 + f];
            const float4 a3 = rowc[(w4 + 3) * 8 + f];
            DOT4(vA, a0, d00, d01, vB);
            DOT4(vA, a1, d10, d11, vB);
            DOT4(vA, a2, d20, d21, vB);
            DOT4(vA, a3, d30, d31, vB);
        }
        const float sA = sqc[t * 128 + lane];
        const float sB = sqc[t * 128 + 64 + lane];
        const int jA = t * 128 + lane, jB = jA + 64;
        const bool vA_ = (pairb & 1u) != 0u;
        const bool vB_ = (pairb & 2u) != 0u;
        MAKE_KEYS(k0, d00, d01, sqr0, row0 + 0);
        MAKE_KEYS(k1, d10, d11, sqr1, row0 + 1);
        MAKE_KEYS(k2, d20, d21, sqr2, row0 + 2);
        MAKE_KEYS(k3, d30, d31, sqr3, row0 + 3);
    }

    // ---- selection (wave-uniform per-row branches)
    unsigned sel0 = 0u, sel1 = 0u, sel2 = 0u, sel3 = 0u;
    if (rv0) SELECT_ROW(k0, w4 + 0, sel0);
    if (rv1) SELECT_ROW(k1, w4 + 1, sel1);
    if (rv2) SELECT_ROW(k2, w4 + 2, sel2);
    if (rv3) SELECT_ROW(k3, w4 + 3, sel3);

    // ---- dense output (plain coalesced dword streams; L2 merges full lines)
#pragma unroll
    for (int tt = 0; tt < 16; ++tt) {
        const int j = tt * 64 + lane;
        {
            const bool s = (sel0 >> tt) & 1u;
            const float dv = s ? sqrtf(__uint_as_float(k0[tt])) : 0.f;
            edges[(size_t)(row0 + 0) * NROW + j] = dv;
            adjm [(size_t)(row0 + 0) * NROW + j] = s ? 1.f : 0.f;
        }
        {
            const bool s = (sel1 >> tt) & 1u;
            const float dv = s ? sqrtf(__uint_as_float(k1[tt])) : 0.f;
            edges[(size_t)(row0 + 1) * NROW + j] = dv;
            adjm [(size_t)(row0 + 1) * NROW + j] = s ? 1.f : 0.f;
        }
        {
            const bool s = (sel2 >> tt) & 1u;
            const float dv = s ? sqrtf(__uint_as_float(k2[tt])) : 0.f;
            edges[(size_t)(row0 + 2) * NROW + j] = dv;
            adjm [(size_t)(row0 + 2) * NROW + j] = s ? 1.f : 0.f;
        }
        {
            const bool s = (sel3 >> tt) & 1u;
            const float dv = s ? sqrtf(__uint_as_float(k3[tt])) : 0.f;
            edges[(size_t)(row0 + 3) * NROW + j] = dv;
            adjm [(size_t)(row0 + 3) * NROW + j] = s ? 1.f : 0.f;
        }
    }
}

extern "C" void kernel_launch(void* const* d_in, const int* in_sizes, int n_in,
                              void* d_out, int out_size, void* d_ws, size_t ws_size,
                              hipStream_t stream)
{
    const float* nodes = (const float*)d_in[0];
    const int*   mask  = (const int*)d_in[1];
    float* out = (float*)d_out;

    dim3 grid(64 * 64);    // 64 batches x 64 blocks (16 rows each)
    dim3 block(256);
    hipLaunchKernelGGL(edge_knn_kernel, grid, block, 0, stream, nodes, mask, out);
}

// Round 5
// 332.242 us; speedup vs baseline: 2.5802x; 1.2017x over previous
//
#include <hip/hip_runtime.h>
#include <math.h>

#define NROW 1024
#define INF_BITS 0x7F800000u
#define WINDOW   4.0e-3f     // > 2*max |d2_f32 - d2_f64| (bound ~8e-4)
#define CLAMP_EPS 1e-12f

typedef float nf4 __attribute__((ext_vector_type(4)));   // native vec for nontemporal builtins

__device__ __forceinline__ unsigned long long ull_min(unsigned long long a, unsigned long long b) {
    return a < b ? a : b;
}

// ---------------------------------------------------------------------------
// Exact top-16 selection per row (unchanged from round 4 — proven correct).
// K[tt] = f32 d^2 bit pattern, column j = tt*64 + lane; INF_BITS for invalid.
// Fast path: ballot-bisection; ambiguity within WINDOW of the 16th value
// triggers the rare exact f64 rescore path with (f64 bits, j) tie-break.
// Uses lane, nbase, rowc, sqr64 from enclosing scope.
// ---------------------------------------------------------------------------
#define SELECT_ROW(K, RLOC, SELOUT)                                                     \
    {                                                                                   \
        unsigned mn = 0xFFFFFFFFu, mx = 0u;                                             \
        _Pragma("unroll")                                                               \
        for (int tt = 0; tt < 16; ++tt) {                                               \
            const unsigned kk_ = K[tt];                                                 \
            mn = kk_ < mn ? kk_ : mn;                                                   \
            const unsigned kf_ = (kk_ < INF_BITS) ? kk_ : 0u;                           \
            mx = kf_ > mx ? kf_ : mx;                                                   \
        }                                                                               \
        _Pragma("unroll")                                                               \
        for (int d = 1; d < 64; d <<= 1) {                                              \
            const unsigned omn = (unsigned)__shfl_xor((int)mn, d);                      \
            const unsigned omx = (unsigned)__shfl_xor((int)mx, d);                      \
            mn = omn < mn ? omn : mn;                                                   \
            mx = omx > mx ? omx : mx;                                                   \
        }                                                                               \
        unsigned lo = mn, hi = mx + 1u;                                                 \
        while (hi - lo > 1u) {                                                          \
            const unsigned mid = lo + ((hi - lo) >> 1);                                 \
            int cnt = 0;                                                                \
            _Pragma("unroll")                                                           \
            for (int tt = 0; tt < 16; ++tt)                                             \
                cnt += __popcll(__ballot(K[tt] < mid));                                 \
            if (cnt >= 16) hi = mid; else lo = mid;                                     \
        }                                                                               \
        const unsigned V = lo;            /* 16th smallest f32 key (bit pattern) */     \
        const float Vw = __uint_as_float(V) + WINDOW;                                   \
        int cS = 0, nE = 0, cW = 0;                                                     \
        unsigned ltm = 0u, eqm = 0u, cm = 0u;                                           \
        _Pragma("unroll")                                                               \
        for (int tt = 0; tt < 16; ++tt) {                                               \
            const unsigned kk_ = K[tt];                                                 \
            const bool l_ = kk_ < V;                                                    \
            const bool e_ = kk_ == V;                                                   \
            const bool c_ = __uint_as_float(kk_) <= Vw;  /* inf never qualifies */      \
            cS += __popcll(__ballot(l_));                                               \
            nE += __popcll(__ballot(e_));                                               \
            cW += __popcll(__ballot(c_));                                               \
            ltm |= (l_ ? 1u : 0u) << tt;                                                \
            eqm |= (e_ ? 1u : 0u) << tt;                                                \
            cm  |= (c_ ? 1u : 0u) << tt;                                                \
        }                                                                               \
        if (cS + nE == 16 && cW == 16) {                                                \
            SELOUT = ltm | eqm;                                                         \
        } else {                                                                        \
            int myj = -1;                                                               \
            {                                                                           \
                int cum = 0;                                                            \
                _Pragma("unroll")                                                       \
                for (int tt = 0; tt < 16; ++tt) {                                       \
                    const unsigned long long bm = __ballot((cm >> tt) & 1u);            \
                    const int pc = __popcll(bm);                                        \
                    if (myj < 0 && lane >= cum && lane < cum + pc) {                    \
                        unsigned long long mm = bm;                                     \
                        for (int z = lane - cum; z > 0; --z) mm &= mm - 1ull;           \
                        myj = tt * 64 + (__ffsll((unsigned long long)mm) - 1);          \
                    }                                                                   \
                    cum += pc;                                                          \
                }                                                                       \
            }                                                                           \
            unsigned long long dbits = ~0ull;                                           \
            if (myj >= 0) {                                                             \
                const float4* cp = (const float4*)(nbase + (size_t)myj * 64);           \
                double sq_ = 0.0, dt_ = 0.0;                                            \
                _Pragma("unroll")                                                       \
                for (int f = 0; f < 8; ++f) {                                           \
                    const float4 v = cp[f];                                             \
                    const float4 a = rowc[(RLOC) * 8 + f];                              \
                    sq_ = fma((double)v.x, (double)v.x, sq_);                           \
                    sq_ = fma((double)v.y, (double)v.y, sq_);                           \
                    sq_ = fma((double)v.z, (double)v.z, sq_);                           \
                    sq_ = fma((double)v.w, (double)v.w, sq_);                           \
                    dt_ = fma((double)v.x, (double)a.x, dt_);                           \
                    dt_ = fma((double)v.y, (double)a.y, dt_);                           \
                    dt_ = fma((double)v.z, (double)a.z, dt_);                           \
                    dt_ = fma((double)v.w, (double)a.w, dt_);                           \
                }                                                                       \
                double d64 = fma(-2.0, dt_, sqr64[RLOC] + sq_);                         \
                d64 = fmax(d64, (double)CLAMP_EPS);                                     \
                dbits = (unsigned long long)__double_as_longlong(d64);                  \
            }                                                                           \
            unsigned selb = 0u;                                                         \
            bool act = (myj >= 0);                                                      \
            for (int round = 0; round < 16; ++round) {                                  \
                unsigned long long best = act ? dbits : ~0ull;                          \
                _Pragma("unroll")                                                       \
                for (int d = 1; d < 64; d <<= 1)                                        \
                    best = ull_min(best,                                                \
                        (unsigned long long)__shfl_xor((long long)best, d));            \
                int pj = (act && dbits == best) ? myj : 0x7FFFFFFF;                     \
                _Pragma("unroll")                                                       \
                for (int d = 1; d < 64; d <<= 1) {                                      \
                    const int o = __shfl_xor(pj, d);                                    \
                    pj = o < pj ? o : pj;                                               \
                }                                                                       \
                if (myj == pj) act = false;                                             \
                if (lane == (pj & 63)) selb |= 1u << (pj >> 6);                         \
            }                                                                           \
            SELOUT = selb;                                                              \
        }                                                                               \
    }

__global__ __launch_bounds__(64) void edge_knn_kernel(
    const float* __restrict__ nodes,
    const int*   __restrict__ mask,
    float*       __restrict__ out)
{
    const int lane = threadIdx.x;              // 64-thread blocks = 1 wave
    const int blk  = blockIdx.x;
    const int b    = blk >> 8;                 // 256 blocks per batch
    const int rowbase = (blk & 255) * 4;       // 4 rows per block

    const int* maskb = mask + b * NROW;
    float* edges = out + (size_t)b * NROW * NROW;
    float* adjm  = out + (size_t)64 * NROW * NROW + (size_t)b * NROW * NROW;

    // ---- fast path: all 4 rows masked -> zero-fill (d_out is poisoned)
    const int anyv = maskb[rowbase] | maskb[rowbase + 1] | maskb[rowbase + 2] | maskb[rowbase + 3];
    if (!anyv) {
        const nf4 z = {0.f, 0.f, 0.f, 0.f};
#pragma unroll
        for (int r = 0; r < 4; ++r) {
            nf4* e4 = reinterpret_cast<nf4*>(edges + (size_t)(rowbase + r) * NROW);
            nf4* a4 = reinterpret_cast<nf4*>(adjm  + (size_t)(rowbase + r) * NROW);
#pragma unroll
            for (int q = 0; q < 4; ++q) {
                __builtin_nontemporal_store(z, e4 + q * 64 + lane);
                __builtin_nontemporal_store(z, a4 + q * 64 + lane);
            }
        }
        return;
    }

    __shared__ float4 rowc[4 * 8];      // 512 B: this wave's 4 row coord vectors
    __shared__ float  sqr32s[4];
    __shared__ double sqr64[4];

    const float* nbase = nodes + (size_t)b * NROW * 64;

    if (lane < 32) {
        const int r = lane >> 3, f = lane & 7;
        rowc[lane] = ((const float4*)(nbase + (size_t)(rowbase + r) * 64))[f];
    }
    __syncthreads();
    if (lane < 4) {
        double s = 0.0;
#pragma unroll
        for (int f = 0; f < 8; ++f) {
            const float4 v = rowc[lane * 8 + f];
            s = fma((double)v.x, (double)v.x, s);
            s = fma((double)v.y, (double)v.y, s);
            s = fma((double)v.z, (double)v.z, s);
            s = fma((double)v.w, (double)v.w, s);
        }
        sqr64[lane] = s;
        sqr32s[lane] = (float)s;
    }
    __syncthreads();

    // column validity bits: bit tt <-> column j = tt*64 + lane
    unsigned mb = 0u;
#pragma unroll
    for (int tt = 0; tt < 16; ++tt)
        mb |= (maskb[tt * 64 + lane] != 0 ? 1u : 0u) << tt;

    const int row0 = rowbase;
    const bool rv0 = maskb[row0 + 0] != 0;
    const bool rv1 = maskb[row0 + 1] != 0;
    const bool rv2 = maskb[row0 + 2] != 0;
    const bool rv3 = maskb[row0 + 3] != 0;
    const float sqr0 = sqr32s[0], sqr1 = sqr32s[1];
    const float sqr2 = sqr32s[2], sqr3 = sqr32s[3];

    unsigned k0[16], k1[16], k2[16], k3[16];

    // ---- main loop: barrier-free, per-lane global column loads (L1/L2-hot)
#pragma unroll
    for (int tt = 0; tt < 16; ++tt) {
        // wave-uniform skip of fully-masked column groups (prefix mask)
        if (__ballot((mb >> tt) & 1u) == 0ull) {
            k0[tt] = INF_BITS; k1[tt] = INF_BITS;
            k2[tt] = INF_BITS; k3[tt] = INF_BITS;
            continue;
        }
        const int j = tt * 64 + lane;
        const float4* cp = (const float4*)(nbase + (size_t)j * 64);
        float4 c[8];
#pragma unroll
        for (int f = 0; f < 8; ++f) c[f] = cp[f];

        // inline column norm — SAME fma order as round-4 sqc pass (bitwise match)
        float sA = 0.f;
#pragma unroll
        for (int f = 0; f < 8; ++f) {
            sA = fmaf(c[f].x, c[f].x, sA); sA = fmaf(c[f].y, c[f].y, sA);
            sA = fmaf(c[f].z, c[f].z, sA); sA = fmaf(c[f].w, c[f].w, sA);
        }

        float d0 = 0.f, d1 = 0.f, d2 = 0.f, d3 = 0.f;
#pragma unroll
        for (int f = 0; f < 8; ++f) {
            const float4 v  = c[f];
            const float4 a0 = rowc[0 * 8 + f];   // wave-uniform broadcast reads
            const float4 a1 = rowc[1 * 8 + f];
            const float4 a2 = rowc[2 * 8 + f];
            const float4 a3 = rowc[3 * 8 + f];
            d0 = fmaf(v.x, a0.x, d0); d0 = fmaf(v.y, a0.y, d0);
            d0 = fmaf(v.z, a0.z, d0); d0 = fmaf(v.w, a0.w, d0);
            d1 = fmaf(v.x, a1.x, d1); d1 = fmaf(v.y, a1.y, d1);
            d1 = fmaf(v.z, a1.z, d1); d1 = fmaf(v.w, a1.w, d1);
            d2 = fmaf(v.x, a2.x, d2); d2 = fmaf(v.y, a2.y, d2);
            d2 = fmaf(v.z, a2.z, d2); d2 = fmaf(v.w, a2.w, d2);
            d3 = fmaf(v.x, a3.x, d3); d3 = fmaf(v.y, a3.y, d3);
            d3 = fmaf(v.z, a3.z, d3); d3 = fmaf(v.w, a3.w, d3);
        }

        const bool cv = (mb >> tt) & 1u;
        float e_;
        e_ = fmaxf(fmaf(-2.f, d0, sqr0 + sA), CLAMP_EPS);
        k0[tt] = (cv && j != row0 + 0) ? __float_as_uint(e_) : INF_BITS;
        e_ = fmaxf(fmaf(-2.f, d1, sqr1 + sA), CLAMP_EPS);
        k1[tt] = (cv && j != row0 + 1) ? __float_as_uint(e_) : INF_BITS;
        e_ = fmaxf(fmaf(-2.f, d2, sqr2 + sA), CLAMP_EPS);
        k2[tt] = (cv && j != row0 + 2) ? __float_as_uint(e_) : INF_BITS;
        e_ = fmaxf(fmaf(-2.f, d3, sqr3 + sA), CLAMP_EPS);
        k3[tt] = (cv && j != row0 + 3) ? __float_as_uint(e_) : INF_BITS;
    }

    // ---- selection (wave-uniform per-row branches)
    unsigned sel0 = 0u, sel1 = 0u, sel2 = 0u, sel3 = 0u;
    if (rv0) SELECT_ROW(k0, 0, sel0);
    if (rv1) SELECT_ROW(k1, 1, sel1);
    if (rv2) SELECT_ROW(k2, 2, sel2);
    if (rv3) SELECT_ROW(k3, 3, sel3);

    // ---- dense output (plain coalesced dword streams; every element written)
#pragma unroll
    for (int tt = 0; tt < 16; ++tt) {
        const int j = tt * 64 + lane;
        {
            const bool s = (sel0 >> tt) & 1u;
            edges[(size_t)(row0 + 0) * NROW + j] = s ? sqrtf(__uint_as_float(k0[tt])) : 0.f;
            adjm [(size_t)(row0 + 0) * NROW + j] = s ? 1.f : 0.f;
        }
        {
            const bool s = (sel1 >> tt) & 1u;
            edges[(size_t)(row0 + 1) * NROW + j] = s ? sqrtf(__uint_as_float(k1[tt])) : 0.f;
            adjm [(size_t)(row0 + 1) * NROW + j] = s ? 1.f : 0.f;
        }
        {
            const bool s = (sel2 >> tt) & 1u;
            edges[(size_t)(row0 + 2) * NROW + j] = s ? sqrtf(__uint_as_float(k2[tt])) : 0.f;
            adjm [(size_t)(row0 + 2) * NROW + j] = s ? 1.f : 0.f;
        }
        {
            const bool s = (sel3 >> tt) & 1u;
            edges[(size_t)(row0 + 3) * NROW + j] = s ? sqrtf(__uint_as_float(k3[tt])) : 0.f;
            adjm [(size_t)(row0 + 3) * NROW + j] = s ? 1.f : 0.f;
        }
    }
}

extern "C" void kernel_launch(void* const* d_in, const int* in_sizes, int n_in,
                              void* d_out, int out_size, void* d_ws, size_t ws_size,
                              hipStream_t stream)
{
    const float* nodes = (const float*)d_in[0];
    const int*   mask  = (const int*)d_in[1];
    float* out = (float*)d_out;

    dim3 grid(64 * 256);   // 64 batches x 256 blocks (4 rows each, 1 wave/block)
    dim3 block(64);
    hipLaunchKernelGGL(edge_knn_kernel, grid, block, 0, stream, nodes, mask, out);
}